// Round 7
// baseline (236.154 us; speedup 1.0000x reference)
//
#include <hip/hip_runtime.h>
#include <hip/hip_bf16.h>

#define NBATCH 256
#define NT 512
#define ND 256
#define NROWS (NBATCH * NT)

typedef __attribute__((ext_vector_type(8))) short short8;
typedef __attribute__((ext_vector_type(4))) float floatx4;

__device__ __forceinline__ unsigned short f2bf(float x) {
    // round-to-nearest-even fp32 -> bf16
    unsigned int u = __float_as_uint(x);
    u += 0x7FFFu + ((u >> 16) & 1u);
    return (unsigned short)(u >> 16);
}

// prep: W fp32 [D,D] (e,d) -> bf16 chunks in MFMA-FRAG ORDER.
// chunk g (16B = 8 bf16) = nb*512 + s*64 + q*16 + m
//   <-> W[e = nb*16 + m][k = q*8 + s*32 .. +8]
__global__ void __launch_bounds__(256) prep_kernel(
    const float* __restrict__ W, unsigned short* __restrict__ wf)
{
    int g  = blockIdx.x * 256 + threadIdx.x;   // 8192 chunks
    int m  = g & 15, q = (g >> 4) & 3, s = (g >> 6) & 7, nb = g >> 9;
    const float* src = W + (nb * 16 + m) * ND + q * 8 + s * 32;
    float4 f0 = *(const float4*)src;
    float4 f1 = *(const float4*)(src + 4);
    short8 v;
    v[0] = (short)f2bf(f0.x); v[1] = (short)f2bf(f0.y);
    v[2] = (short)f2bf(f0.z); v[3] = (short)f2bf(f0.w);
    v[4] = (short)f2bf(f1.x); v[5] = (short)f2bf(f1.y);
    v[6] = (short)f2bf(f1.z); v[7] = (short)f2bf(f1.w);
    *(short8*)(wf + (long)g * 8) = v;
}

// scores[bt] = sum_e tanh(sum_d ip[bt,d]*W[e,d] + bias[e]) * ctx[e]
// 1024 blocks x 256 thr (4 waves). EVERY global access is lane-linear:
//  - ip: staged per block (128 rows) in two 32KB halves, fp32 read coalesced,
//    bf16 written to XOR-swizzled frag-order LDS (conflict-free both sides),
//    A-frags pulled out via ds_read_b128 -> registers.
//  - W: staged from frag-ordered wf (chunk-linear) in 32KB quarters (as R6).
// Same 32KB LDS reused for A-halves then W-quarters.
__global__ void __launch_bounds__(256, 3) scores_kernel(
    const float* __restrict__ ip,             // [B*T, D] fp32
    const unsigned short* __restrict__ wf,    // frag-ordered W bf16
    const float* __restrict__ bias,           // [D] fp32
    const float* __restrict__ ctx,            // [D] fp32
    float* __restrict__ scores)               // [B*T] fp32
{
    __shared__ __align__(16) char lds[32768];
    short8* lds16 = (short8*)lds;

    const int tid  = threadIdx.x;
    const int lane = tid & 63;
    const int wv   = tid >> 6;        // wave 0..3
    const int m    = lane & 15;       // A row / W e-col within tile
    const int q    = lane >> 4;       // k-quad
    const long brow0 = (long)blockIdx.x * 128;
    const long row0  = brow0 + wv * 32;

    // ---- stage ip 128 rows as bf16 frag-order (two 64-row halves) ----
    // half = 2048 chunks of 32B fp32 -> 16B bf16. Chunk C: row r=C>>5, j=C&31
    // covers k=[j*8, j*8+8). Frag chunk c = (j>>2)*64 + (j&3)*16 + (r&15),
    // swizzled c^(j&7): writer (2 rows x 32 j) and reader (16 m x 4 q) both
    // spread 8 lanes/bank-group -> conflict-free.
    short8 a[2][8];
#pragma unroll 1
    for (int h = 0; h < 2; ++h) {
        if (h) __syncthreads();               // prior half's frag reads done
#pragma unroll
        for (int u = 0; u < 8; ++u) {
            int C = u * 256 + tid;
            int r = C >> 5, j = C & 31;
            const float* src = ip + (brow0 + h * 64 + r) * ND + j * 8;
            float4 f0 = *(const float4*)src;
            float4 f1 = *(const float4*)(src + 4);
            short8 v;
            v[0] = (short)f2bf(f0.x); v[1] = (short)f2bf(f0.y);
            v[2] = (short)f2bf(f0.z); v[3] = (short)f2bf(f0.w);
            v[4] = (short)f2bf(f1.x); v[5] = (short)f2bf(f1.y);
            v[6] = (short)f2bf(f1.z); v[7] = (short)f2bf(f1.w);
            int tau = r >> 4;
            int cc  = (j >> 2) * 64 + (j & 3) * 16 + (r & 15);
            lds16[tau * 512 + (cc ^ (j & 7))] = v;
        }
        __syncthreads();
        if ((wv >> 1) == h) {                 // waves owning this half
            const int wl = wv & 1;
#pragma unroll
            for (int tile = 0; tile < 2; ++tile) {
                const int tau = wl * 2 + tile;
#pragma unroll
                for (int s = 0; s < 8; ++s) {
                    int j  = q + 4 * s;
                    int cc = s * 64 + q * 16 + m;
                    a[tile][s] = lds16[tau * 512 + (cc ^ (j & 7))];
                }
            }
        }
    }
    __syncthreads();                          // A reads done; LDS free for W

    float sc0[4] = {0.f, 0.f, 0.f, 0.f};
    float sc1[4] = {0.f, 0.f, 0.f, 0.f};
    const short8* wchunks = (const short8*)wf;

#pragma unroll 1
    for (int stage = 0; stage < 4; ++stage) {
        if (stage) __syncthreads();           // prior quarter's reads done
#pragma unroll
        for (int u = 0; u < 8; ++u) {
            int c = u * 256 + tid;
            lds16[c] = wchunks[stage * 2048 + c];   // chunk-linear, coalesced
        }
        __syncthreads();

#pragma unroll 1
        for (int nbl = 0; nbl < 4; ++nbl) {
            const int e = (stage * 4 + nbl) * 16 + m;
            const short8* wp = lds16 + nbl * 512 + lane;   // lane-linear b128
            short8 w[8];
#pragma unroll
            for (int s = 0; s < 8; ++s) w[s] = wp[s * 64];
            floatx4 acc0 = {0.f, 0.f, 0.f, 0.f};
            floatx4 acc1 = {0.f, 0.f, 0.f, 0.f};
#pragma unroll
            for (int s = 0; s < 8; ++s) {
                acc0 = __builtin_amdgcn_mfma_f32_16x16x32_bf16(a[0][s], w[s], acc0, 0, 0, 0);
                acc1 = __builtin_amdgcn_mfma_f32_16x16x32_bf16(a[1][s], w[s], acc1, 0, 0, 0);
            }
            const float be  = bias[e];        // 1KB tables, L1-hot
            const float ce  = ctx[e];
            const float ce2 = ce + ce;
#pragma unroll
            for (int r = 0; r < 4; ++r) {     // acc[r] = D[row=q*4+r][col=m]
                float x0 = acc0[r] + be;
                float x1 = acc1[r] + be;
                // tanh(x)*ce = ce - ce2 * rcp(exp(2x)+1)
                float t0 = __builtin_amdgcn_rcpf(__expf(x0 + x0) + 1.f);
                float t1 = __builtin_amdgcn_rcpf(__expf(x1 + x1) + 1.f);
                sc0[r] = __builtin_fmaf(-ce2, t0, sc0[r] + ce);
                sc1[r] = __builtin_fmaf(-ce2, t1, sc1[r] + ce);
            }
        }
    }

    // sum over 16 e-cols spread across lanes sharing a quad (xor lane bits 0..3)
#pragma unroll
    for (int off = 8; off >= 1; off >>= 1) {
#pragma unroll
        for (int r = 0; r < 4; ++r) {
            sc0[r] += __shfl_xor(sc0[r], off, 64);
            sc1[r] += __shfl_xor(sc1[r], off, 64);
        }
    }
    if (m == 0) {
#pragma unroll
        for (int r = 0; r < 4; ++r) {
            scores[row0 + q * 4 + r]      = sc0[r];
            scores[row0 + 16 + q * 4 + r] = sc1[r];
        }
    }
}

// wsum: block (b, dquad of 64 floats). In-block softmax over scores[b,:],
// then out[b, d] = sum_t attn[t] * ip[b,t,d] for d in the 64-float slice.
__global__ void __launch_bounds__(256) wsum_kernel(
    const float* __restrict__ ip,       // [B,T,D] fp32
    const float* __restrict__ scores,   // [B,T] fp32
    float* __restrict__ out)            // [B,D] fp32
{
    __shared__ float attn_s[NT];
    __shared__ float red[8];
    __shared__ float partial[16][64];

    const int b  = blockIdx.x >> 2;
    const int dq = blockIdx.x & 3;      // d-slice: [dq*64, dq*64+64)
    const int tid  = threadIdx.x;
    const int lane = tid & 63;
    const int wv   = tid >> 6;          // wave 0..3

    // softmax: each thread handles scores tid and tid+256
    float s0 = scores[(long)b * NT + tid];
    float s1 = scores[(long)b * NT + tid + 256];
    float mx = fmaxf(s0, s1);
#pragma unroll
    for (int off = 32; off >= 1; off >>= 1) mx = fmaxf(mx, __shfl_xor(mx, off, 64));
    if (lane == 0) red[wv] = mx;
    __syncthreads();
    mx = fmaxf(fmaxf(red[0], red[1]), fmaxf(red[2], red[3]));
    float e0 = __expf(s0 - mx), e1 = __expf(s1 - mx);
    float sm = e0 + e1;
#pragma unroll
    for (int off = 32; off >= 1; off >>= 1) sm += __shfl_xor(sm, off, 64);
    __syncthreads();                    // red max-reads done before rewrite
    if (lane == 0) red[4 + wv] = sm;
    __syncthreads();
    sm = red[4] + red[5] + red[6] + red[7];
    float inv = 1.f / sm;
    attn_s[tid]       = e0 * inv;
    attn_s[tid + 256] = e1 * inv;
    __syncthreads();

    // weighted sum: thread = (dg float4 in slice: 0..15, t-slice ts: 0..15 of 32 t)
    const int dg = tid & 15;
    const int ts = tid >> 4;
    const float4* base = (const float4*)(ip + (long)b * NT * ND + dq * 64) + dg;
    float a0 = 0.f, a1 = 0.f, a2 = 0.f, a3 = 0.f;
#pragma unroll 8
    for (int t = ts * 32; t < ts * 32 + 32; ++t) {
        float w = attn_s[t];
        float4 v = base[t * 64];        // row stride = 64 float4
        a0 += w * v.x; a1 += w * v.y; a2 += w * v.z; a3 += w * v.w;
    }
    partial[ts][dg * 4 + 0] = a0;
    partial[ts][dg * 4 + 1] = a1;
    partial[ts][dg * 4 + 2] = a2;
    partial[ts][dg * 4 + 3] = a3;
    __syncthreads();
    if (tid < 64) {
        float r = 0.f;
#pragma unroll
        for (int i = 0; i < 16; ++i) r += partial[i][tid];
        out[(long)b * ND + dq * 64 + tid] = r;
    }
}

extern "C" void kernel_launch(void* const* d_in, const int* in_sizes, int n_in,
                              void* d_out, int out_size, void* d_ws, size_t ws_size,
                              hipStream_t stream) {
    const float* ip   = (const float*)d_in[0];
    const float* W    = (const float*)d_in[1];
    const float* bias = (const float*)d_in[2];
    const float* ctx  = (const float*)d_in[3];

    unsigned short* wf = (unsigned short*)d_ws;   // 128 KB, frag-ordered W
    float* scores = (float*)((char*)d_ws + ND * ND * sizeof(unsigned short)); // 512 KB

    prep_kernel<<<32, 256, 0, stream>>>(W, wf);
    scores_kernel<<<NROWS / 128, 256, 0, stream>>>(ip, wf, bias, ctx, scores);
    wsum_kernel<<<NBATCH * 4, 256, 0, stream>>>(ip, scores, (float*)d_out);
}

// Round 8
// 232.646 us; speedup vs baseline: 1.0151x; 1.0151x over previous
//
#include <hip/hip_runtime.h>
#include <hip/hip_bf16.h>

#define NBATCH 256
#define NT 512
#define ND 256
#define NROWS (NBATCH * NT)

typedef __attribute__((ext_vector_type(8))) short short8;
typedef __attribute__((ext_vector_type(4))) float floatx4;

__device__ __forceinline__ unsigned short f2bf(float x) {
    // round-to-nearest-even fp32 -> bf16
    unsigned int u = __float_as_uint(x);
    u += 0x7FFFu + ((u >> 16) & 1u);
    return (unsigned short)(u >> 16);
}

// prep: W fp32 [D,D] (e,d) -> bf16 chunks in MFMA-FRAG ORDER.
// chunk g (16B = 8 bf16) = nb*512 + s*64 + q*16 + m
//   <-> W[e = nb*16 + m][k = q*8 + s*32 .. +8]
__global__ void __launch_bounds__(256) prep_kernel(
    const float* __restrict__ W, unsigned short* __restrict__ wf)
{
    int g  = blockIdx.x * 256 + threadIdx.x;   // 8192 chunks
    int m  = g & 15, q = (g >> 4) & 3, s = (g >> 6) & 7, nb = g >> 9;
    const float* src = W + (nb * 16 + m) * ND + q * 8 + s * 32;
    float4 f0 = *(const float4*)src;
    float4 f1 = *(const float4*)(src + 4);
    short8 v;
    v[0] = (short)f2bf(f0.x); v[1] = (short)f2bf(f0.y);
    v[2] = (short)f2bf(f0.z); v[3] = (short)f2bf(f0.w);
    v[4] = (short)f2bf(f1.x); v[5] = (short)f2bf(f1.y);
    v[6] = (short)f2bf(f1.z); v[7] = (short)f2bf(f1.w);
    *(short8*)(wf + (long)g * 8) = v;
}

// scores[bt] = sum_e tanh(sum_d ip[bt,d]*W[e,d] + bias[e]) * ctx[e]
// FINE-GRAIN: 2048 blocks x 256 thr (4 waves), 64 rows/block, ONE 16-row
// MFMA tile per wave. 2x total waves vs R7 (8192), ~4 blocks/CU resident
// (LDS 32KB, VGPR<=128) -> bursty load phases of different blocks overlap.
// A loads batched 8-deep before conversion (force MLP). W staged to LDS
// from frag-ordered wf (chunk-linear coalesced), frag reads ds_read_b128.
__global__ void __launch_bounds__(256, 4) scores_kernel(
    const float* __restrict__ ip,             // [B*T, D] fp32
    const unsigned short* __restrict__ wf,    // frag-ordered W bf16
    const float* __restrict__ bias,           // [D] fp32
    const float* __restrict__ ctx,            // [D] fp32
    float* __restrict__ scores)               // [B*T] fp32
{
    __shared__ __align__(16) char wsm[32768];   // one W quarter, frag order
    short8* lds16 = (short8*)wsm;

    const int tid  = threadIdx.x;
    const int lane = tid & 63;
    const int wv   = tid >> 6;        // wave 0..3
    const int m    = lane & 15;       // A row / W e-col within tile
    const int q    = lane >> 4;       // k-quad
    const long row0 = (long)blockIdx.x * 64 + wv * 16;

    // ---- A fragments: ONE tile (16 rows), loads batched 8-deep ----
    short8 a[8];
    {
        const float* ar = ip + (row0 + m) * ND + q * 8;
        float4 raw[8];
#pragma unroll
        for (int g = 0; g < 2; ++g) {
            // batch: 8 independent float4 loads (s = 4g..4g+3, halves 0/1)
#pragma unroll
            for (int i = 0; i < 4; ++i) {
                raw[2 * i]     = *(const float4*)(ar + (4 * g + i) * 32);
                raw[2 * i + 1] = *(const float4*)(ar + (4 * g + i) * 32 + 4);
            }
#pragma unroll
            for (int i = 0; i < 4; ++i) {
                short8 v;
                v[0] = (short)f2bf(raw[2 * i].x); v[1] = (short)f2bf(raw[2 * i].y);
                v[2] = (short)f2bf(raw[2 * i].z); v[3] = (short)f2bf(raw[2 * i].w);
                v[4] = (short)f2bf(raw[2 * i + 1].x); v[5] = (short)f2bf(raw[2 * i + 1].y);
                v[6] = (short)f2bf(raw[2 * i + 1].z); v[7] = (short)f2bf(raw[2 * i + 1].w);
                a[4 * g + i] = v;
            }
        }
    }

    float sc[4] = {0.f, 0.f, 0.f, 0.f};
    const short8* wchunks = (const short8*)wf;

#pragma unroll 1
    for (int stage = 0; stage < 4; ++stage) {
        if (stage) __syncthreads();           // prior quarter's reads done
#pragma unroll
        for (int u = 0; u < 8; ++u) {
            int c = u * 256 + tid;
            lds16[c] = wchunks[stage * 2048 + c];   // chunk-linear, coalesced
        }
        __syncthreads();

#pragma unroll 1
        for (int nbl = 0; nbl < 4; ++nbl) {
            const int e = (stage * 4 + nbl) * 16 + m;
            const short8* wp = lds16 + nbl * 512 + lane;   // lane-linear b128
            short8 w[8];
#pragma unroll
            for (int s = 0; s < 8; ++s) w[s] = wp[s * 64];
            floatx4 acc = {0.f, 0.f, 0.f, 0.f};
#pragma unroll
            for (int s = 0; s < 8; ++s)
                acc = __builtin_amdgcn_mfma_f32_16x16x32_bf16(a[s], w[s], acc, 0, 0, 0);
            const float be  = bias[e];        // 1KB tables, L1-hot
            const float ce  = ctx[e];
            const float ce2 = ce + ce;
#pragma unroll
            for (int r = 0; r < 4; ++r) {     // acc[r] = D[row=q*4+r][col=m]
                float x = acc[r] + be;
                // tanh(x)*ce = ce - ce2 * rcp(exp(2x)+1)
                float t = __builtin_amdgcn_rcpf(__expf(x + x) + 1.f);
                sc[r] = __builtin_fmaf(-ce2, t, sc[r] + ce);
            }
        }
    }

    // sum over 16 e-cols spread across lanes sharing a quad (xor lane bits 0..3)
#pragma unroll
    for (int off = 8; off >= 1; off >>= 1) {
#pragma unroll
        for (int r = 0; r < 4; ++r)
            sc[r] += __shfl_xor(sc[r], off, 64);
    }
    if (m == 0) {
#pragma unroll
        for (int r = 0; r < 4; ++r)
            scores[row0 + q * 4 + r] = sc[r];
    }
}

// wsum: block (b, dquad of 64 floats). In-block softmax over scores[b,:],
// then out[b, d] = sum_t attn[t] * ip[b,t,d] for d in the 64-float slice.
__global__ void __launch_bounds__(256) wsum_kernel(
    const float* __restrict__ ip,       // [B,T,D] fp32
    const float* __restrict__ scores,   // [B,T] fp32
    float* __restrict__ out)            // [B,D] fp32
{
    __shared__ float attn_s[NT];
    __shared__ float red[8];
    __shared__ float partial[16][64];

    const int b  = blockIdx.x >> 2;
    const int dq = blockIdx.x & 3;      // d-slice: [dq*64, dq*64+64)
    const int tid  = threadIdx.x;
    const int lane = tid & 63;
    const int wv   = tid >> 6;          // wave 0..3

    // softmax: each thread handles scores tid and tid+256
    float s0 = scores[(long)b * NT + tid];
    float s1 = scores[(long)b * NT + tid + 256];
    float mx = fmaxf(s0, s1);
#pragma unroll
    for (int off = 32; off >= 1; off >>= 1) mx = fmaxf(mx, __shfl_xor(mx, off, 64));
    if (lane == 0) red[wv] = mx;
    __syncthreads();
    mx = fmaxf(fmaxf(red[0], red[1]), fmaxf(red[2], red[3]));
    float e0 = __expf(s0 - mx), e1 = __expf(s1 - mx);
    float sm = e0 + e1;
#pragma unroll
    for (int off = 32; off >= 1; off >>= 1) sm += __shfl_xor(sm, off, 64);
    __syncthreads();                    // red max-reads done before rewrite
    if (lane == 0) red[4 + wv] = sm;
    __syncthreads();
    sm = red[4] + red[5] + red[6] + red[7];
    float inv = 1.f / sm;
    attn_s[tid]       = e0 * inv;
    attn_s[tid + 256] = e1 * inv;
    __syncthreads();

    // weighted sum: thread = (dg float4 in slice: 0..15, t-slice ts: 0..15 of 32 t)
    const int dg = tid & 15;
    const int ts = tid >> 4;
    const float4* base = (const float4*)(ip + (long)b * NT * ND + dq * 64) + dg;
    float a0 = 0.f, a1 = 0.f, a2 = 0.f, a3 = 0.f;
#pragma unroll 8
    for (int t = ts * 32; t < ts * 32 + 32; ++t) {
        float w = attn_s[t];
        float4 v = base[t * 64];        // row stride = 64 float4
        a0 += w * v.x; a1 += w * v.y; a2 += w * v.z; a3 += w * v.w;
    }
    partial[ts][dg * 4 + 0] = a0;
    partial[ts][dg * 4 + 1] = a1;
    partial[ts][dg * 4 + 2] = a2;
    partial[ts][dg * 4 + 3] = a3;
    __syncthreads();
    if (tid < 64) {
        float r = 0.f;
#pragma unroll
        for (int i = 0; i < 16; ++i) r += partial[i][tid];
        out[(long)b * ND + dq * 64 + tid] = r;
    }
}

extern "C" void kernel_launch(void* const* d_in, const int* in_sizes, int n_in,
                              void* d_out, int out_size, void* d_ws, size_t ws_size,
                              hipStream_t stream) {
    const float* ip   = (const float*)d_in[0];
    const float* W    = (const float*)d_in[1];
    const float* bias = (const float*)d_in[2];
    const float* ctx  = (const float*)d_in[3];

    unsigned short* wf = (unsigned short*)d_ws;   // 128 KB, frag-ordered W
    float* scores = (float*)((char*)d_ws + ND * ND * sizeof(unsigned short)); // 512 KB

    prep_kernel<<<32, 256, 0, stream>>>(W, wf);
    scores_kernel<<<NROWS / 64, 256, 0, stream>>>(ip, wf, bias, ctx, scores);
    wsum_kernel<<<NBATCH * 4, 256, 0, stream>>>(ip, scores, (float*)d_out);
}